// Round 5
// baseline (137.433 us; speedup 1.0000x reference)
//
#include <hip/hip_runtime.h>
#include <cstdint>
#include <cstddef>

#define N_PTS 4096
#define KDIM  512
#define NFEAT 5

typedef __attribute__((ext_vector_type(8))) short bf16x8;   // 8 bf16 = 4 VGPRs
typedef __attribute__((ext_vector_type(4))) float f32x4;
typedef uint32_t u32;

// round-to-nearest-even fp32 -> bf16 (inputs finite)
__device__ inline unsigned short f2bf(float f) {
  union { float f; u32 u; } v; v.f = f;
  u32 r = (v.u + 0x7fffu + ((v.u >> 16) & 1u)) >> 16;
  return (unsigned short)r;
}

__device__ inline void bf2f2(u32 u, float& a, float& b) {
  union { u32 u; float f; } x, y;
  x.u = u << 16; y.u = u & 0xffff0000u;
  a = x.f; b = y.f;
}

// ---------------------------------------------------------------------------
// Kernel 1: repack X (fp32, row-major) into FRAGMENT-MAJOR bf16 Xf and
// compute row squared norms. Layout: Xf[(p*16 + c)*512 + l*8 .. +8] holds
// X[p*16 + (l&15)][c*32 + (l>>4)*8 .. +8] — exactly the mfma_16x16x32_bf16
// A/B fragment for 16-row panel p, 32-k chunk c, lane l. One wave per row.
// ---------------------------------------------------------------------------
__global__ __launch_bounds__(256) void prep_kernel(const float* __restrict__ X,
                                                   short* __restrict__ Xf,
                                                   float* __restrict__ sq,
                                                   float* __restrict__ gsum) {
  const int t = threadIdx.x;
  if (blockIdx.x == 0 && t == 0) *gsum = 0.f;
  const int r = blockIdx.x * 4 + (t >> 6);   // wave w handles row r
  const int g = t & 63;                      // 8-element k-granule
  const float* src = X + (size_t)r * KDIM + g * 8;
  const float4 u0 = ((const float4*)src)[0];
  const float4 u1 = ((const float4*)src)[1];
  union { unsigned short s[8]; uint4 q; } pk;
  pk.s[0] = f2bf(u0.x); pk.s[1] = f2bf(u0.y);
  pk.s[2] = f2bf(u0.z); pk.s[3] = f2bf(u0.w);
  pk.s[4] = f2bf(u1.x); pk.s[5] = f2bf(u1.y);
  pk.s[6] = f2bf(u1.z); pk.s[7] = f2bf(u1.w);
  const int p = r >> 4, c = g >> 2, l = ((g & 3) << 4) | (r & 15);
  *(uint4*)(Xf + (size_t)(p * 16 + c) * 512 + l * 8) = pk.q;
  float s = u0.x * u0.x + u0.y * u0.y + u0.z * u0.z + u0.w * u0.w +
            u1.x * u1.x + u1.y * u1.y + u1.z * u1.z + u1.w * u1.w;
#pragma unroll
  for (int off = 32; off; off >>= 1) s += __shfl_down(s, off);
  if (g == 0) sq[r] = s;
}

// ---------------------------------------------------------------------------
// Kernel 2: BARRIER-FREE distance GEMM. 128x128 tile per 256-thread block,
// each wave owns a 64x64 quadrant. Fragments load straight from the
// fragment-major Xf as coalesced dwordx4 (base + lane*16) — no LDS staging,
// no __syncthreads in the K-loop; register double-buffer (next chunk's 8
// loads in flight under current 16 MFMAs). Xf (4 MB) lives in L2/L1.
// Epilogue: fragment-ordered bf16 Dw (dense 16B stores) + gsum atomic.
// ---------------------------------------------------------------------------
__global__ __launch_bounds__(256, 3) void dist_kernel(
    const short* __restrict__ Xf, const float* __restrict__ sq,
    unsigned short* __restrict__ Dw, float* __restrict__ gsum) {
  __shared__ float red[4];
  const int tid = threadIdx.x;
  const int lane = tid & 63;
  const int wid = tid >> 6;
  const int wave_m = wid >> 1, wave_n = wid & 1;
  const int lhi = lane >> 4, llo = lane & 15;
  const int bm = blockIdx.y, bn = blockIdx.x;

  // panel stride = 16*512 = 8192 shorts; chunk stride = 512 shorts
  const short* baseA = Xf + (size_t)(bm * 8 + wave_m * 4) * 8192 + lane * 8;
  const short* baseB = Xf + (size_t)(bn * 8 + wave_n * 4) * 8192 + lane * 8;

  f32x4 acc[4][4];
#pragma unroll
  for (int i = 0; i < 4; ++i)
#pragma unroll
    for (int j = 0; j < 4; ++j) acc[i][j] = (f32x4){0.f, 0.f, 0.f, 0.f};

  bf16x8 ca[4], cb[4];
#pragma unroll
  for (int i = 0; i < 4; ++i) {
    ca[i] = *(const bf16x8*)(baseA + i * 8192);
    cb[i] = *(const bf16x8*)(baseB + i * 8192);
  }

#pragma unroll
  for (int c = 0; c < 16; ++c) {
    bf16x8 na[4], nb[4];
    if (c < 15) {
#pragma unroll
      for (int i = 0; i < 4; ++i) {
        na[i] = *(const bf16x8*)(baseA + (c + 1) * 512 + i * 8192);
        nb[i] = *(const bf16x8*)(baseB + (c + 1) * 512 + i * 8192);
      }
    }
#pragma unroll
    for (int i = 0; i < 4; ++i)
#pragma unroll
      for (int j = 0; j < 4; ++j)
        acc[i][j] =
            __builtin_amdgcn_mfma_f32_16x16x32_bf16(ca[i], cb[j], acc[i][j], 0, 0, 0);
    if (c < 15) {
#pragma unroll
      for (int i = 0; i < 4; ++i) { ca[i] = na[i]; cb[i] = nb[i]; }
    }
  }

  // epilogue: C/D layout col=lane&15, row=(lane>>4)*4+reg
  float lsum = 0.f;
  const int gi0 = bm * 128, gj0 = bn * 128;
  const int r_base = wave_m * 64 + lhi * 4;
  const int c_base = wave_n * 64 + llo;
  float sqj[4];
#pragma unroll
  for (int j = 0; j < 4; ++j) sqj[j] = sq[gj0 + c_base + j * 16];

  const size_t tile_base = ((size_t)(bm * 32 + bn)) * 16384 + (size_t)wid * 4096;

#pragma unroll
  for (int i = 0; i < 4; ++i) {
    union { unsigned short s[16]; uint4 q[2]; } pk;
#pragma unroll
    for (int rr = 0; rr < 4; ++rr) {
      const int r = r_base + i * 16 + rr;
      const float sqi = sq[gi0 + r];
#pragma unroll
      for (int j = 0; j < 4; ++j) {
        const int c = c_base + j * 16;
        float d2 = sqi + sqj[j] - 2.f * acc[i][j][rr];
        float dd = sqrtf(fmaxf(d2, 0.f));
        if (gi0 + r == gj0 + c) dd = 0.f;  // exact-zero diagonal
        lsum += dd;
        pk.s[rr * 4 + j] = f2bf(dd);
      }
    }
    unsigned short* dst = Dw + tile_base + (size_t)i * 1024;
    *(uint4*)(dst + lane * 8) = pk.q[0];
    *(uint4*)(dst + 512 + lane * 8) = pk.q[1];
  }

#pragma unroll
  for (int off = 32; off; off >>= 1) lsum += __shfl_down(lsum, off);
  if (lane == 0) red[wid] = lsum;
  __syncthreads();
  if (tid == 0) atomicAdd(gsum, red[0] + red[1] + red[2] + red[3]);
}

// ---------------------------------------------------------------------------
// Kernel 3: read fragment-ordered bf16 Dw (dense uint4), 5-way exp,
// write canonical fp32 out (64B-segment dword stores per 16-lane group).
// ---------------------------------------------------------------------------
__global__ __launch_bounds__(256) void rbf_kernel(
    const unsigned short* __restrict__ Dw, const float* __restrict__ gsum,
    const float* __restrict__ mult, float* __restrict__ out) {
  const float bw = *gsum * (1.0f / ((float)N_PTS * (float)(N_PTS - 1)));
  float c[NFEAT];
#pragma unroll
  for (int f = 0; f < NFEAT; ++f) c[f] = -1.0f / (bw * mult[f]);

  const int b = blockIdx.x;       // 0..1023 tile id
  const int bm = b >> 5, bn = b & 31;
  const int tid = threadIdx.x;
  const int lane = tid & 63;
  const int wid = tid >> 6;
  const int wave_m = wid >> 1, wave_n = wid & 1;
  const int lhi = lane >> 4, llo = lane & 15;

  const size_t tile_base = (size_t)b * 16384 + (size_t)wid * 4096;
  const int gi0 = bm * 128 + wave_m * 64 + lhi * 4;
  const int gj0 = bn * 128 + wave_n * 64 + llo;

#pragma unroll
  for (int i = 0; i < 4; ++i) {
    const unsigned short* src = Dw + tile_base + (size_t)i * 1024;
    const uint4 q0 = *(const uint4*)(src + lane * 8);
    const uint4 q1 = *(const uint4*)(src + 512 + lane * 8);
    float v[16];
    bf2f2(q0.x, v[0], v[1]);   bf2f2(q0.y, v[2], v[3]);
    bf2f2(q0.z, v[4], v[5]);   bf2f2(q0.w, v[6], v[7]);
    bf2f2(q1.x, v[8], v[9]);   bf2f2(q1.y, v[10], v[11]);
    bf2f2(q1.z, v[12], v[13]); bf2f2(q1.w, v[14], v[15]);

    float o[16];
#pragma unroll
    for (int e = 0; e < 16; ++e) {
      float a = 0.f;
#pragma unroll
      for (int f = 0; f < NFEAT; ++f) a += __expf(v[e] * c[f]);
      o[e] = a;
    }

#pragma unroll
    for (int rr = 0; rr < 4; ++rr) {
      float* orow = out + (size_t)(gi0 + i * 16 + rr) * N_PTS + gj0;
#pragma unroll
      for (int j = 0; j < 4; ++j) orow[j * 16] = o[rr * 4 + j];
    }
  }
}

extern "C" void kernel_launch(void* const* d_in, const int* in_sizes, int n_in,
                              void* d_out, int out_size, void* d_ws, size_t ws_size,
                              hipStream_t stream) {
  const float* X = (const float*)d_in[0];
  const float* mult = (const float*)d_in[1];
  float* out = (float*)d_out;

  // ws: gsum@0 | sq@1024 (16KB) | Xf@17408 (4MB, fragment-major) | Dw @ +4MB (32MB)
  char* ws = (char*)d_ws;
  float* gsum = (float*)ws;
  float* sq = (float*)(ws + 1024);
  short* Xf = (short*)(ws + 1024 + N_PTS * sizeof(float));
  unsigned short* Dw = (unsigned short*)(ws + 1024 + N_PTS * sizeof(float) +
                                         (size_t)N_PTS * KDIM * sizeof(short));

  prep_kernel<<<N_PTS / 4, 256, 0, stream>>>(X, Xf, sq, gsum);
  dist_kernel<<<dim3(32, 32), 256, 0, stream>>>(Xf, sq, Dw, gsum);
  rbf_kernel<<<1024, 256, 0, stream>>>(Dw, gsum, mult, out);
}